// Round 1
// baseline (159.667 us; speedup 1.0000x reference)
//
#include <hip/hip_runtime.h>
#include <math.h>

// SpectralModule: out[b,c,n,e] = sum_f |rfft13(x[b,c,n,:])[f]|/13 * W[f,e] + b[e]
// Shapes: x [32,64,128,13] f32, W [7,512] f32, b [512] f32, out [32,64,128,512] f32.
// Memory-bound by the 512 MiB output write.

constexpr int T = 13;
constexpr int F = 7;    // T/2 + 1
constexpr int E = 512;

__global__ __launch_bounds__(256) void spectral_kernel(
    const float* __restrict__ x,
    const float* __restrict__ W,
    const float* __restrict__ bias,
    float* __restrict__ out,
    int nrows)
{
    __shared__ float s_cos[F * T];
    __shared__ float s_sin[F * T];

    const int tid = threadIdx.x;

    // Build twiddle table once per block. Angle reduced mod 13 for accuracy.
    if (tid < F * T) {
        const int f = tid / T;
        const int t = tid - f * T;
        const int k = (f * t) % T;
        const float ang = -2.0f * 3.14159265358979323846f * (float)k / (float)T;
        float s, c;
        sincosf(ang, &s, &c);
        s_cos[tid] = c;
        s_sin[tid] = s;
    }
    __syncthreads();

    const int lane = tid & 63;
    const int wave = tid >> 6;      // 4 waves per block, one row each
    const int e0 = lane * 8;        // each lane owns 8 output columns

    // Hoist W (7 x 8 floats) and bias (8 floats) into registers once.
    float4 w0[F], w1[F];
#pragma unroll
    for (int f = 0; f < F; ++f) {
        w0[f] = *reinterpret_cast<const float4*>(W + f * E + e0);
        w1[f] = *reinterpret_cast<const float4*>(W + f * E + e0 + 4);
    }
    const float4 b0 = *reinterpret_cast<const float4*>(bias + e0);
    const float4 b1 = *reinterpret_cast<const float4*>(bias + e0 + 4);

    const float inv_t = 1.0f / (float)T;
    const long long stride = (long long)gridDim.x * 4;

    for (long long row = (long long)blockIdx.x * 4 + wave; row < nrows; row += stride) {
        const float* __restrict__ xr = x + row * T;

        // Lanes 0..6 each compute one rfft bin magnitude.
        float mag = 0.0f;
        if (lane < F) {
            float re = 0.0f, im = 0.0f;
            const float* __restrict__ cs = s_cos + lane * T;
            const float* __restrict__ sn = s_sin + lane * T;
#pragma unroll
            for (int t = 0; t < T; ++t) {
                const float v = xr[t];
                re = fmaf(v, cs[t], re);
                im = fmaf(v, sn[t], im);
            }
            mag = sqrtf(fmaf(re, re, im * im)) * inv_t;
        }

        // Broadcast the 7 magnitudes to all 64 lanes.
        float m[F];
#pragma unroll
        for (int f = 0; f < F; ++f) m[f] = __shfl(mag, f, 64);

        // 8 outputs per lane: acc = b + sum_f m[f] * W[f, e]
        float4 a0 = b0, a1 = b1;
#pragma unroll
        for (int f = 0; f < F; ++f) {
            a0.x = fmaf(m[f], w0[f].x, a0.x);
            a0.y = fmaf(m[f], w0[f].y, a0.y);
            a0.z = fmaf(m[f], w0[f].z, a0.z);
            a0.w = fmaf(m[f], w0[f].w, a0.w);
            a1.x = fmaf(m[f], w1[f].x, a1.x);
            a1.y = fmaf(m[f], w1[f].y, a1.y);
            a1.z = fmaf(m[f], w1[f].z, a1.z);
            a1.w = fmaf(m[f], w1[f].w, a1.w);
        }

        float4* __restrict__ o = reinterpret_cast<float4*>(out + row * E + e0);
        o[0] = a0;
        o[1] = a1;
    }
}

extern "C" void kernel_launch(void* const* d_in, const int* in_sizes, int n_in,
                              void* d_out, int out_size, void* d_ws, size_t ws_size,
                              hipStream_t stream) {
    const float* x = (const float*)d_in[0];
    const float* W = (const float*)d_in[1];
    const float* b = (const float*)d_in[2];
    float* out = (float*)d_out;

    const int nrows = in_sizes[0] / T;   // 32*64*128 = 262144

    // Memory-bound: ~2048 blocks (8/CU), grid-stride over rows (4 rows/block/iter).
    int blocks = 2048;
    const int rows_per_iter = 4;
    if (blocks * rows_per_iter > nrows) blocks = (nrows + rows_per_iter - 1) / rows_per_iter;

    spectral_kernel<<<blocks, 256, 0, stream>>>(x, W, b, out, nrows);
}